// Round 1
// baseline (492.082 us; speedup 1.0000x reference)
//
#include <hip/hip_runtime.h>
#include <hip/hip_bf16.h>

// ARIMA(P=64, D=1, Q=32) forecast, STEPS=2048.
// Only the last 65 elements of x are needed:
//   dx[j] = x[j+1]-x[j]; window0 = dx[S-65 .. S-2]
//   pred_t = dot(w_ar, window) + b_ar + b_ma   (MA term is dot(w_ma, 0)=0)
//   window <- [window[1:], pred_t]
//   out[t] = x[S-1] + cumsum(pred)[t]
//
// One wave of 64 lanes: lane k owns w_ar[k] and window[k].
// Per step: butterfly __shfl_xor reduce for the dot, __shfl_down shift.

__global__ __launch_bounds__(64)
void arima_scan_kernel(const float* __restrict__ x, int S,
                       const float* __restrict__ w_ar,
                       const float* __restrict__ b_ar_p,
                       const float* __restrict__ b_ma_p,
                       const int* __restrict__ steps_p,
                       float* __restrict__ out) {
    const int lane = threadIdx.x;          // 0..63, single wave
    const float w = w_ar[lane];

    // window0[k] = x[S-64+k] - x[S-65+k]
    float window = x[S - 64 + lane] - x[S - 65 + lane];

    const float c = b_ar_p[0] + b_ma_p[0]; // b_ar + ma_out (ma_out == b_ma)
    const float x_last = x[S - 1];
    const int steps = steps_p[0];

    float csum = 0.0f;
    for (int t = 0; t < steps; ++t) {
        // dot(w_ar, window) via wave butterfly reduce (all lanes get the sum)
        float prod = w * window;
        #pragma unroll
        for (int off = 1; off < 64; off <<= 1)
            prod += __shfl_xor(prod, off, 64);

        const float pred = prod + c;
        csum += pred;
        if (lane == 0)
            out[t] = x_last + csum;

        // shift window left by one, append pred at position 63
        const float up = __shfl_down(window, 1, 64);
        window = (lane == 63) ? pred : up;
    }
}

extern "C" void kernel_launch(void* const* d_in, const int* in_sizes, int n_in,
                              void* d_out, int out_size, void* d_ws, size_t ws_size,
                              hipStream_t stream) {
    const float* x      = (const float*)d_in[0];
    const float* w_ar   = (const float*)d_in[1];
    const float* b_ar_p = (const float*)d_in[2];
    // d_in[3] = w_ma (unused: multiplied by zeros in the reference)
    const float* b_ma_p = (const float*)d_in[4];
    const int*   steps  = (const int*)d_in[5];
    float* out = (float*)d_out;
    const int S = in_sizes[0];

    arima_scan_kernel<<<1, 64, 0, stream>>>(x, S, w_ar, b_ar_p, b_ma_p, steps, out);
}

// Round 3
// 22.597 us; speedup vs baseline: 21.7765x; 21.7765x over previous
//
#include <hip/hip_runtime.h>
#include <hip/hip_bf16.h>

// ARIMA(P=64,D=1,Q=32), STEPS=2048, blocked formulation.
//
// preds follow: pred_t = dot(w_ar, window_t) + c,  c = b_ar + b_ma.
// window evolves as a companion system; blocking 64 steps:
//   y_block = T * state + d,   next state = y_block,
// with row j of T:  u_0 = w,  u_{j+1}[k] = u_j[k-1] + w[k]*u_j[63]  (u[-1]=0),
// and d_0 = c,  d_{j+1} = d_j + c*u_j[63].
// 32 serial 64x64 matvecs replace 2048 serial butterfly reductions.
//
// NOTE: __builtin_amdgcn_readlane is int(int,int) — floats MUST be bit-cast,
// else the compiler value-converts float->int (R1 bug: all broadcasts were 0).

#define T_STRIDE 68  // floats; 272B rows: 16B-aligned for float4, breaks bank conflicts

__device__ __forceinline__ float lane_bcast(float v, int l) {
    return __int_as_float(__builtin_amdgcn_readlane(__float_as_int(v), l));
}

__global__ __launch_bounds__(64)
void arima_block_kernel(const float* __restrict__ x, int S,
                        const float* __restrict__ w_ar,
                        const float* __restrict__ b_ar_p,
                        const float* __restrict__ b_ma_p,
                        const int* __restrict__ steps_p,
                        float* __restrict__ out) {
    __shared__ float T_lds[64 * T_STRIDE];
    __shared__ float d_lds[64];

    const int lane = threadIdx.x;                 // single wave of 64
    const float w = w_ar[lane];
    const float c = b_ar_p[0] + b_ma_p[0];
    const float x_last = x[S - 1];
    const int steps = steps_p[0];

    // ---- phase 1: build T rows (u_j) and d via the cheap generator ----
    float u = w;           // u_0, lane k holds u[k]
    float e = c;           // d_0
    T_lds[lane] = u;
    if (lane == 0) d_lds[0] = e;
    for (int j = 1; j < 64; ++j) {
        const float u63 = lane_bcast(u, 63);
        const float up  = __shfl_up(u, 1, 64);
        e = fmaf(c, u63, e);
        u = ((lane == 0) ? 0.0f : up) + w * u63;
        T_lds[j * T_STRIDE + lane] = u;
        if (lane == 0) d_lds[j] = e;
    }
    __syncthreads();

    // preload row `lane` of T into registers (compile-time indexed -> VGPRs)
    float trow[64];
    #pragma unroll
    for (int m = 0; m < 16; ++m) {
        const float4 v = *reinterpret_cast<const float4*>(&T_lds[lane * T_STRIDE + 4 * m]);
        trow[4*m+0] = v.x; trow[4*m+1] = v.y; trow[4*m+2] = v.z; trow[4*m+3] = v.w;
    }
    const float dl = d_lds[lane];

    // ---- phase 2: 32 serial block-matvecs + cumsum ----
    float state = x[S - 64 + lane] - x[S - 65 + lane];   // window0
    float base = x_last;                                  // running integration offset

    const int nblk = (steps + 63) >> 6;
    for (int b = 0; b < nblk; ++b) {
        float a0 = 0.f, a1 = 0.f, a2 = 0.f, a3 = 0.f;
        #pragma unroll
        for (int k = 0; k < 64; k += 4) {
            a0 = fmaf(trow[k+0], lane_bcast(state, k+0), a0);
            a1 = fmaf(trow[k+1], lane_bcast(state, k+1), a1);
            a2 = fmaf(trow[k+2], lane_bcast(state, k+2), a2);
            a3 = fmaf(trow[k+3], lane_bcast(state, k+3), a3);
        }
        const float y = ((a0 + a1) + (a2 + a3)) + dl;     // y_block[lane]
        state = y;                                        // critical chain: y -> readlanes

        // off-critical-path: inclusive prefix sum + integrated output
        float ps = y;
        #pragma unroll
        for (int off = 1; off < 64; off <<= 1) {
            const float n = __shfl_up(ps, off, 64);
            if (lane >= off) ps += n;
        }
        const int t = b * 64 + lane;
        if (t < steps) out[t] = base + ps;
        base += lane_bcast(ps, 63);
    }
}

extern "C" void kernel_launch(void* const* d_in, const int* in_sizes, int n_in,
                              void* d_out, int out_size, void* d_ws, size_t ws_size,
                              hipStream_t stream) {
    const float* x      = (const float*)d_in[0];
    const float* w_ar   = (const float*)d_in[1];
    const float* b_ar_p = (const float*)d_in[2];
    // d_in[3] = w_ma (unused: multiplied by zeros in the reference)
    const float* b_ma_p = (const float*)d_in[4];
    const int*   steps  = (const int*)d_in[5];
    float* out = (float*)d_out;
    const int S = in_sizes[0];

    arima_block_kernel<<<1, 64, 0, stream>>>(x, S, w_ar, b_ar_p, b_ma_p, steps, out);
}

// Round 4
// 18.297 us; speedup vs baseline: 26.8945x; 1.2350x over previous
//
#include <hip/hip_runtime.h>
#include <hip/hip_bf16.h>

// ARIMA(P=64,D=1,Q=32), STEPS=2048, blocked formulation, v3.
//
// pred_t = dot(w_ar, window_t) + c,  c = b_ar + b_ma;  out = x[S-1] + cumsum(pred).
// Blocked: y_blk = T*state + d, state' = y_blk  (32 serial 64x64 matvecs).
// Rows of T: u_0 = w,  u_{j+1}[k] = u_j[k-1] + w[k]*r_j,  r_j = u_j[63].
// d_j = c*(1 + sum_{i<j} r_i).
//
// v3 changes vs v2 (both serial chains cut to issue floor):
//  - generator batched x4: per iter, 4 INDEPENDENT shfl_up (1..4) + scalar r-chain
//      u_{j+s}[k] = u_j[k-s] + sum_{i<s} w[k-(s-1-i)]*r_{j+i}
//      r_{j+1}=u_j[62]+w63*r_j; r_{j+2}=u_j[61]+w62*r_j+w63*r_{j+1}; ...
//  - main loop: matvec only; y -> LDS fire-and-forget (no prefix on chain)
//  - epilogue: 32 prefix sums batched per shfl round (6 latency hits total)
//
// NOTE: __builtin_amdgcn_readlane is int(int,int) — floats MUST be bit-cast.

#define T_STRIDE 68   // 17 dwords-of-4: lane L row-read starts at bank 17L%32 -> conflict-free b128

__device__ __forceinline__ float lane_bcast(float v, int l) {
    return __int_as_float(__builtin_amdgcn_readlane(__float_as_int(v), l));
}

__global__ __launch_bounds__(64)
void arima_block_kernel(const float* __restrict__ x, int S,
                        const float* __restrict__ w_ar,
                        const float* __restrict__ b_ar_p,
                        const float* __restrict__ b_ma_p,
                        const int* __restrict__ steps_p,
                        float* __restrict__ out) {
    __shared__ float T_lds[65 * T_STRIDE];   // rows 0..63 (+1 overflow scratch row)
    __shared__ float y_lds[32 * 64];

    const int lane = threadIdx.x;            // single wave of 64
    const float w = w_ar[lane];
    const float c = b_ar_p[0] + b_ma_p[0];
    const float x_last = x[S - 1];
    const int steps = steps_p[0];

    // window0 loads issued early (latency hidden under phase 1)
    const float x_hi = x[S - 64 + lane];
    const float x_lo = x[S - 65 + lane];

    // per-lane shifted copies of w: wshS[k] = w[k-S] (0 for k<S)
    float wsh1 = __shfl_up(w, 1, 64); wsh1 = (lane >= 1) ? wsh1 : 0.0f;
    float wsh2 = __shfl_up(w, 2, 64); wsh2 = (lane >= 2) ? wsh2 : 0.0f;
    float wsh3 = __shfl_up(w, 3, 64); wsh3 = (lane >= 3) ? wsh3 : 0.0f;
    // scalar tail weights
    const float sw63 = lane_bcast(w, 63);
    const float sw62 = lane_bcast(w, 62);
    const float sw61 = lane_bcast(w, 61);

    // ---- phase 1: build rows of T, 4 per iteration ----
    float u = w;                              // u_0
    T_lds[lane] = u;
    for (int j = 0; j < 64; j += 4) {
        const float r0  = lane_bcast(u, 63);
        const float b62 = lane_bcast(u, 62);
        const float b61 = lane_bcast(u, 61);
        const float b60 = lane_bcast(u, 60);
        float s1 = __shfl_up(u, 1, 64); s1 = (lane >= 1) ? s1 : 0.0f;
        float s2 = __shfl_up(u, 2, 64); s2 = (lane >= 2) ? s2 : 0.0f;
        float s3 = __shfl_up(u, 3, 64); s3 = (lane >= 3) ? s3 : 0.0f;
        float s4 = __shfl_up(u, 4, 64); s4 = (lane >= 4) ? s4 : 0.0f;
        // scalar r-chain (short FMA deps, starts as soon as readlanes land)
        const float r1 = fmaf(sw63, r0, b62);
        const float r2 = fmaf(sw63, r1, fmaf(sw62, r0, b61));
        const float r3 = fmaf(sw63, r2, fmaf(sw62, r1, fmaf(sw61, r0, b60)));
        // four new rows
        const float u1 = fmaf(w, r0, s1);
        const float u2 = fmaf(w, r1, fmaf(wsh1, r0, s2));
        const float u3 = fmaf(w, r2, fmaf(wsh1, r1, fmaf(wsh2, r0, s3)));
        const float u4 = fmaf(w, r3, fmaf(wsh1, r2, fmaf(wsh2, r1, fmaf(wsh3, r0, s4))));
        T_lds[(j + 1) * T_STRIDE + lane] = u1;
        T_lds[(j + 2) * T_STRIDE + lane] = u2;
        T_lds[(j + 3) * T_STRIDE + lane] = u3;
        T_lds[(j + 4) * T_STRIDE + lane] = u4;   // j=60 writes scratch row 64
        u = u4;
    }
    __syncthreads();

    // preload row `lane` into registers (contiguous, 16B-aligned, conflict-free)
    float trow[64];
    #pragma unroll
    for (int m = 0; m < 16; ++m) {
        const float4 v = *reinterpret_cast<const float4*>(&T_lds[lane * T_STRIDE + 4 * m]);
        trow[4*m+0] = v.x; trow[4*m+1] = v.y; trow[4*m+2] = v.z; trow[4*m+3] = v.w;
    }

    // d_lane = c*(1 + sum_{i<lane} r_i);  r_lane = trow[63]
    float ip = trow[63];
    #pragma unroll
    for (int off = 1; off < 64; off <<= 1) {
        const float n = __shfl_up(ip, off, 64);
        if (lane >= off) ip += n;
    }
    float ex = __shfl_up(ip, 1, 64); ex = (lane >= 1) ? ex : 0.0f;
    const float dl = c * (1.0f + ex);

    // ---- phase 2: serial block matvecs, cumsum deferred ----
    float state = x_hi - x_lo;                // window0
    const int nblk = (steps + 63) >> 6;       // 32 for steps=2048

    for (int b = 0; b < nblk; ++b) {
        float a0 = 0.f, a1 = 0.f, a2 = 0.f, a3 = 0.f;
        #pragma unroll
        for (int k = 0; k < 64; k += 4) {
            a0 = fmaf(trow[k+0], lane_bcast(state, k+0), a0);
            a1 = fmaf(trow[k+1], lane_bcast(state, k+1), a1);
            a2 = fmaf(trow[k+2], lane_bcast(state, k+2), a2);
            a3 = fmaf(trow[k+3], lane_bcast(state, k+3), a3);
        }
        const float y = ((a0 + a1) + (a2 + a3)) + dl;
        y_lds[b * 64 + lane] = y;             // fire-and-forget
        state = y;                            // the only serial dependence
    }
    __syncthreads();

    // ---- epilogue: batched prefix sums + integration + stores ----
    float yv[32];
    #pragma unroll
    for (int b = 0; b < 32; ++b)
        yv[b] = (b < nblk) ? y_lds[b * 64 + lane] : 0.0f;

    #pragma unroll
    for (int off = 1; off < 64; off <<= 1) {
        #pragma unroll
        for (int b = 0; b < 32; ++b) {
            const float n = __shfl_up(yv[b], off, 64);
            if (lane >= off) yv[b] += n;
        }
    }

    float base = x_last;
    #pragma unroll
    for (int b = 0; b < 32; ++b) {
        const int t = b * 64 + lane;
        if (t < steps) out[t] = base + yv[b];
        base += lane_bcast(yv[b], 63);
    }
}

extern "C" void kernel_launch(void* const* d_in, const int* in_sizes, int n_in,
                              void* d_out, int out_size, void* d_ws, size_t ws_size,
                              hipStream_t stream) {
    const float* x      = (const float*)d_in[0];
    const float* w_ar   = (const float*)d_in[1];
    const float* b_ar_p = (const float*)d_in[2];
    // d_in[3] = w_ma (unused: multiplied by zeros in the reference)
    const float* b_ma_p = (const float*)d_in[4];
    const int*   steps  = (const int*)d_in[5];
    float* out = (float*)d_out;
    const int S = in_sizes[0];

    arima_block_kernel<<<1, 64, 0, stream>>>(x, S, w_ar, b_ar_p, b_ma_p, steps, out);
}